// Round 1
// baseline (1938.419 us; speedup 1.0000x reference)
//
#include <hip/hip_runtime.h>
#include <math.h>

// Problem constants
#define BATCH 32
#define SEQ 256
#define EMBD 256
#define HDIM 256          // per-direction hidden
#define G4H 1024          // 4*H gates per direction
#define TAGS 12
#define START_IDX 10
#define STOP_IDX 11
#define NEGV -10000.0f

// Recurrence weight split: first KRES K-values resident in VGPRs, rest streamed
#define KRES 80                 // 20 float4
#define KSTREAM_GROUPS 44       // (256-80)/4

// ---------------- Workspace layout (floats) ----------------
// xg     : [2][8192][1024]            = 16,777,216
// x      : [8192][256]                =  2,097,152
// wpack  : [2][44][1024] float4       =    360,448 floats
// h_all  : [32][256][512]             =  4,194,304
// feats  : [32][256][12]              =     98,304
#define WS_XG    0
#define WS_X     16777216
#define WS_WPACK 18874368
#define WS_HALL  19234816
#define WS_FEATS 23429120
// total 23,527,424 floats = 94.1 MB

// ---------------- Kernel 1: gather embeddings ----------------
__global__ void gather_x(const int* __restrict__ sent, const float* __restrict__ emb,
                         float* __restrict__ x) {
    int m = blockIdx.x;            // 8192 positions (b*256+s)
    int lane = threadIdx.x;        // 64
    long long row = sent[m];
    float4 v = *(const float4*)(emb + row * EMBD + lane * 4);
    *(float4*)(x + (size_t)m * EMBD + lane * 4) = v;
}

// ---------------- Kernel 2: pack streamed tail of whh, coalesced layout ----
// wpack[dir][k4][g] = whh_dir[g][KRES + 4*k4 .. +3]
__global__ void pack_whh(const float* __restrict__ whh_f, const float* __restrict__ whh_b,
                         float4* __restrict__ pack) {
    int idx = blockIdx.x * 256 + threadIdx.x;      // 2*44*1024 = 90112
    if (idx >= 2 * KSTREAM_GROUPS * G4H) return;
    int g = idx & 1023;
    int r = idx >> 10;
    int k4 = r % KSTREAM_GROUPS;
    int dir = r / KSTREAM_GROUPS;
    const float* w = dir ? whh_b : whh_f;
    pack[idx] = *(const float4*)(w + (size_t)g * HDIM + KRES + k4 * 4);
}

// ---------------- Kernel 3: xg GEMM  C[8192][2048] ----------------
// A[m][k] = x[m][k], B[n][k] = wih_{dir}[g][k]; C -> xg[dir][m][g] + bih + bhh
__launch_bounds__(256)
__global__ void gemm_xg(const float* __restrict__ x,
                        const float* __restrict__ wih_f, const float* __restrict__ wih_b,
                        const float* __restrict__ bih_f, const float* __restrict__ bhh_f,
                        const float* __restrict__ bih_b, const float* __restrict__ bhh_b,
                        float* __restrict__ xg) {
    __shared__ __align__(16) float as[8][128];
    __shared__ __align__(16) float bs[8][128];
    int m0 = blockIdx.x * 128;     // 64 tiles
    int n0 = blockIdx.y * 128;     // 16 tiles
    int tid = threadIdx.x;
    int tx = tid & 15, ty = tid >> 4;
    int lr = tid >> 1;             // 0..127 tile row
    int lh = (tid & 1) * 4;        // k offset 0 or 4

    const float* arow = x + (size_t)(m0 + lr) * EMBD;
    const float* brow;
    {
        int n = n0 + lr;
        const float* w = (n < G4H) ? wih_f : wih_b;
        brow = w + (size_t)(n & 1023) * EMBD;
    }

    float acc[8][8];
    #pragma unroll
    for (int i = 0; i < 8; i++)
        #pragma unroll
        for (int j = 0; j < 8; j++) acc[i][j] = 0.f;

    for (int k0 = 0; k0 < EMBD; k0 += 8) {
        float4 av = *(const float4*)(arow + k0 + lh);
        float4 bv = *(const float4*)(brow + k0 + lh);
        __syncthreads();
        as[lh + 0][lr] = av.x; as[lh + 1][lr] = av.y; as[lh + 2][lr] = av.z; as[lh + 3][lr] = av.w;
        bs[lh + 0][lr] = bv.x; bs[lh + 1][lr] = bv.y; bs[lh + 2][lr] = bv.z; bs[lh + 3][lr] = bv.w;
        __syncthreads();
        #pragma unroll
        for (int kk = 0; kk < 8; kk++) {
            float4 a0 = *(const float4*)&as[kk][ty * 8];
            float4 a1 = *(const float4*)&as[kk][ty * 8 + 4];
            float4 b0 = *(const float4*)&bs[kk][tx * 8];
            float4 b1 = *(const float4*)&bs[kk][tx * 8 + 4];
            float a[8] = {a0.x, a0.y, a0.z, a0.w, a1.x, a1.y, a1.z, a1.w};
            float b[8] = {b0.x, b0.y, b0.z, b0.w, b1.x, b1.y, b1.z, b1.w};
            #pragma unroll
            for (int i = 0; i < 8; i++)
                #pragma unroll
                for (int j = 0; j < 8; j++) acc[i][j] += a[i] * b[j];
        }
    }

    // epilogue: + bih + bhh (reference order), store to xg[dir] base
    int n = n0 + tx * 8;                 // tile stays within one dir (1024 % 128 == 0)
    int dir = n >> 10, g0 = n & 1023;
    const float* bih = dir ? bih_b : bih_f;
    const float* bhh = dir ? bhh_b : bhh_f;
    float bi[8], bh[8];
    #pragma unroll
    for (int j = 0; j < 8; j++) { bi[j] = bih[g0 + j]; bh[j] = bhh[g0 + j]; }
    float* ob = xg + (size_t)dir * 8192 * G4H;
    #pragma unroll
    for (int i = 0; i < 8; i++) {
        int m = m0 + ty * 8 + i;
        float v[8];
        #pragma unroll
        for (int j = 0; j < 8; j++) v[j] = (acc[i][j] + bi[j]) + bh[j];
        *(float4*)(ob + (size_t)m * G4H + g0)     = make_float4(v[0], v[1], v[2], v[3]);
        *(float4*)(ob + (size_t)m * G4H + g0 + 4) = make_float4(v[4], v[5], v[6], v[7]);
    }
}

// ---------------- Kernel 4: LSTM recurrence ----------------
// One WG per (batch, direction). Thread g owns gate g (K=256 dot with h).
__launch_bounds__(1024)
__global__ void lstm_rec(const float* __restrict__ xg,
                         const float* __restrict__ whh_f, const float* __restrict__ whh_b,
                         const float4* __restrict__ wpack,
                         float* __restrict__ h_all) {
    int blk = blockIdx.x;          // 64
    int dir = blk & 1, b = blk >> 1;
    int g = threadIdx.x;           // 0..1023
    const float* whh = dir ? whh_b : whh_f;
    const float4* wp = wpack + (size_t)dir * KSTREAM_GROUPS * G4H;
    const float* xgb = xg + (size_t)dir * 8192 * G4H + (size_t)b * SEQ * G4H;

    __shared__ __align__(16) float h_lds[HDIM];
    __shared__ float gates[G4H];

    // resident weights: whh[g][0:KRES)
    float4 wr[KRES / 4];
    #pragma unroll
    for (int i = 0; i < KRES / 4; i++)
        wr[i] = *(const float4*)(whh + (size_t)g * HDIM + i * 4);

    float c = 0.f;
    if (g < HDIM) h_lds[g] = 0.f;
    __syncthreads();

    for (int t = 0; t < SEQ; t++) {
        int s = dir ? (SEQ - 1 - t) : t;
        float acc = xgb[(size_t)s * G4H + g];
        // resident portion (LDS reads are wave-uniform broadcasts)
        #pragma unroll
        for (int i = 0; i < KRES / 4; i++) {
            float4 h4 = *(const float4*)&h_lds[i * 4];
            acc += wr[i].x * h4.x + wr[i].y * h4.y + wr[i].z * h4.z + wr[i].w * h4.w;
        }
        // streamed portion (coalesced float4, L2-resident)
        #pragma unroll 4
        for (int i = 0; i < KSTREAM_GROUPS; i++) {
            float4 w4 = wp[(size_t)i * G4H + g];
            float4 h4 = *(const float4*)&h_lds[KRES + i * 4];
            acc += w4.x * h4.x + w4.y * h4.y + w4.z * h4.z + w4.w * h4.w;
        }
        gates[g] = acc;
        __syncthreads();
        if (g < HDIM) {
            float gi = gates[g], gf = gates[HDIM + g], gg = gates[2 * HDIM + g], go = gates[3 * HDIM + g];
            float si = 1.f / (1.f + expf(-gi));
            float sf = 1.f / (1.f + expf(-gf));
            float so = 1.f / (1.f + expf(-go));
            c = sf * c + si * tanhf(gg);
            float h = so * tanhf(c);
            h_lds[g] = h;
            h_all[((size_t)b * SEQ + s) * 512 + dir * HDIM + g] = h;
        }
        __syncthreads();
    }
}

// ---------------- Kernel 5: output projection (feats) ----------------
__global__ void feats_kernel(const float* __restrict__ h_all, const float* __restrict__ w_out,
                             const float* __restrict__ b_out, float* __restrict__ feats) {
    int p = blockIdx.x;            // 8192
    int lane = threadIdx.x;        // 64
    const float* h = h_all + (size_t)p * 512;
    for (int f = 0; f < TAGS; f++) {
        float s = 0.f;
        const float* w = w_out + f * 512;
        #pragma unroll
        for (int k = 0; k < 512; k += 64) s += h[k + lane] * w[k + lane];
        #pragma unroll
        for (int off = 32; off; off >>= 1) s += __shfl_down(s, off);
        if (lane == 0) feats[(size_t)p * TAGS + f] = s + b_out[f];
    }
}

// ---------------- Kernel 6: Viterbi decode ----------------
__global__ void viterbi_kernel(const float* __restrict__ feats, const float* __restrict__ trans,
                               float* __restrict__ out) {
    int b = blockIdx.x;            // 32
    int t = threadIdx.x;           // 64
    __shared__ float fv[TAGS], fvn[TAGS], tr[TAGS * TAGS];
    __shared__ int bp[SEQ][TAGS];  // 12 KB

    for (int i = t; i < TAGS * TAGS; i += 64) tr[i] = trans[i];
    if (t < TAGS) fv[t] = (t == START_IDX) ? 0.f : NEGV;
    __syncthreads();

    const float* fb = feats + (size_t)b * SEQ * TAGS;
    for (int s = 0; s < SEQ; s++) {
        if (t < TAGS) {
            float best = fv[0] + tr[t * TAGS + 0];
            int bi = 0;
            #pragma unroll
            for (int prev = 1; prev < TAGS; prev++) {
                float v = fv[prev] + tr[t * TAGS + prev];
                if (v > best) { best = v; bi = prev; }   // first-index argmax
            }
            bp[s][t] = bi;
            fvn[t] = best + fb[s * TAGS + t];
        }
        __syncthreads();
        if (t < TAGS) fv[t] = fvn[t];
        __syncthreads();
    }

    if (t == 0) {
        float best = fv[0] + tr[STOP_IDX * TAGS + 0];
        int bi = 0;
        #pragma unroll
        for (int p = 1; p < TAGS; p++) {
            float v = fv[p] + tr[STOP_IDX * TAGS + p];
            if (v > best) { best = v; bi = p; }
        }
        out[b] = best;                                   // score
        float* path = out + BATCH + (size_t)b * SEQ;
        int tag = bi;
        path[SEQ - 1] = (float)tag;
        for (int s = SEQ - 1; s >= 1; s--) {
            tag = bp[s][tag];
            path[s - 1] = (float)tag;
        }
    }
}

// ---------------- Launch ----------------
extern "C" void kernel_launch(void* const* d_in, const int* in_sizes, int n_in,
                              void* d_out, int out_size, void* d_ws, size_t ws_size,
                              hipStream_t stream) {
    const int*   sent  = (const int*)d_in[0];
    const float* emb   = (const float*)d_in[1];
    const float* wih_f = (const float*)d_in[2];
    const float* whh_f = (const float*)d_in[3];
    const float* bih_f = (const float*)d_in[4];
    const float* bhh_f = (const float*)d_in[5];
    const float* wih_b = (const float*)d_in[6];
    const float* whh_b = (const float*)d_in[7];
    const float* bih_b = (const float*)d_in[8];
    const float* bhh_b = (const float*)d_in[9];
    const float* w_out = (const float*)d_in[10];
    const float* b_out = (const float*)d_in[11];
    const float* trans = (const float*)d_in[12];
    float* ws    = (float*)d_ws;
    float* xg    = ws + WS_XG;
    float* x     = ws + WS_X;
    float* wpack = ws + WS_WPACK;
    float* h_all = ws + WS_HALL;
    float* feats = ws + WS_FEATS;
    float* out   = (float*)d_out;

    gather_x<<<BATCH * SEQ, 64, 0, stream>>>(sent, emb, x);
    pack_whh<<<(2 * KSTREAM_GROUPS * G4H + 255) / 256, 256, 0, stream>>>(whh_f, whh_b, (float4*)wpack);
    gemm_xg<<<dim3(64, 16), 256, 0, stream>>>(x, wih_f, wih_b, bih_f, bhh_f, bih_b, bhh_b, xg);
    lstm_rec<<<64, 1024, 0, stream>>>(xg, whh_f, whh_b, (const float4*)wpack, h_all);
    feats_kernel<<<BATCH * SEQ, 64, 0, stream>>>(h_all, w_out, b_out, feats);
    viterbi_kernel<<<BATCH, 64, 0, stream>>>(feats, trans, out);
}